// Round 1
// baseline (520.772 us; speedup 1.0000x reference)
//
#include <hip/hip_runtime.h>
#include <hip/hip_bf16.h>

// Problem constants (fixed by the reference)
#define N_B   4
#define T_S   2048
#define DM    1024
#define HEADS 16
#define DK    64

typedef unsigned short ubf16;  // raw bf16 bits
typedef __attribute__((ext_vector_type(8))) short short8;     // MFMA A/B frag (8 bf16)
typedef __attribute__((ext_vector_type(4))) float floatx4;    // 16x16 MFMA C/D frag
typedef __attribute__((ext_vector_type(16))) float floatx16;  // 32x32 MFMA C/D frag
typedef __attribute__((ext_vector_type(4))) unsigned uintx4;

__device__ __forceinline__ float bf2f(unsigned short u) {
    return __uint_as_float(((unsigned)u) << 16);
}
__device__ __forceinline__ unsigned short f2bf(float f) {
    unsigned u = __float_as_uint(f);
    u += 0x7fff + ((u >> 16) & 1);   // round-to-nearest-even
    return (unsigned short)(u >> 16);
}
// packed f32x2 -> bf16x2 (RNE), low word = a
__device__ __forceinline__ unsigned cvtpk(float a, float b) {
    unsigned r;
    asm("v_cvt_pk_bf16_f32 %0, %1, %2" : "=v"(r) : "v"(a), "v"(b));
    return r;
}
// swap a.hi32lanes <-> b.lo32lanes (gfx950)
__device__ __forceinline__ void pswap(unsigned& a, unsigned& b) {
    asm volatile("v_permlane32_swap_b32 %0, %1" : "+v"(a), "+v"(b));
}

// async global->LDS DMA, 16 B per lane; LDS dest = wave-uniform base + lane*16
__device__ __forceinline__ void async_copy16(const ubf16* g, ubf16* l) {
    __builtin_amdgcn_global_load_lds(
        (const __attribute__((address_space(1))) void*)g,
        (__attribute__((address_space(3))) void*)l, 16, 0, 0);
}

// ---------------------------------------------------------------------------
// fp32 -> bf16 bulk convert (8 elems/thread)
// ---------------------------------------------------------------------------
__global__ __launch_bounds__(256) void cvt_bf16(
    const float* __restrict__ X, ubf16* __restrict__ Y, int n8)
{
    const int i = blockIdx.x * 256 + threadIdx.x;
    if (i < n8) {
        const float4 a = ((const float4*)X)[2 * i];
        const float4 b = ((const float4*)X)[2 * i + 1];
        ushort4 o0, o1;
        o0.x = f2bf(a.x); o0.y = f2bf(a.y); o0.z = f2bf(a.z); o0.w = f2bf(a.w);
        o1.x = f2bf(b.x); o1.y = f2bf(b.y); o1.z = f2bf(b.z); o1.w = f2bf(b.w);
        ((ushort4*)Y)[2 * i]     = o0;
        ((ushort4*)Y)[2 * i + 1] = o1;
    }
}

// ---------------------------------------------------------------------------
// Weight transpose+convert: W fp32 [k][n] (1024x1024) -> Wt bf16 [n][k].
// ---------------------------------------------------------------------------
__global__ __launch_bounds__(256) void wtrans(
    const float* __restrict__ W, ubf16* __restrict__ Wt)
{
    __shared__ ubf16 T[64][72];
    const int tid = threadIdx.x;
    const int kb = blockIdx.x * 64, nb = blockIdx.y * 64;
    const int r = tid >> 2, cc = (tid & 3) * 16;
    const float* p = W + (size_t)(kb + r) * 1024 + nb + cc;
#pragma unroll
    for (int t = 0; t < 16; t += 4) {
        float4 x = *(const float4*)(p + t);
        T[r][cc + t + 0] = f2bf(x.x);
        T[r][cc + t + 1] = f2bf(x.y);
        T[r][cc + t + 2] = f2bf(x.z);
        T[r][cc + t + 3] = f2bf(x.w);
    }
    __syncthreads();
    ubf16 buf[16];
#pragma unroll
    for (int t = 0; t < 16; ++t) buf[t] = T[cc + t][r];   // transpose read
    ubf16* op = Wt + (size_t)(nb + r) * 1024 + kb + cc;
    *(uint4*)op       = *(uint4*)buf;
    *(uint4*)(op + 8) = *(uint4*)(buf + 8);
}

// ---------------------------------------------------------------------------
// MFMA GEMM (unchanged): Y = X[M,1024](bf16) @ Wt^T + bias.  Tile 128x128,
// BK=32, 4 waves (2x2), 64x64 C per wave, global_load_lds width=16 staging.
// EPI: 0 = bf16 heads [n][h][t][d]; 1 = bf16 V-transposed [n][h][d][t];
//      2 = fp32 row-major [m][1024].
// ---------------------------------------------------------------------------
template <int EPI>
__global__ __launch_bounds__(256) void gemm_mfma(
    const ubf16* __restrict__ X, const ubf16* __restrict__ Wt,
    const float* __restrict__ bias, void* __restrict__ Yv)
{
    __shared__ ubf16 As[128][32];  // [m][k], 64 B rows, unpadded (DMA layout)
    __shared__ ubf16 Bs[128][32];  // [n][k]

    const int tid = threadIdx.x;
    const int mb = blockIdx.x * 128, nb = blockIdx.y * 128;
    const int w = tid >> 6, lid = tid & 63, quad = lid >> 4, l15 = lid & 15;
    const int wr = (w >> 1) * 64, wc = (w & 1) * 64;

    // DMA source pattern: lane covers row w*32 + (lid>>2), col chunk (lid&3)*8
    const int drow = w * 32 + (lid >> 2);
    const int dcol = (lid & 3) * 8;

    floatx4 acc[4][4] = {};

    for (int kb = 0; kb < 1024; kb += 32) {
        if (kb) __syncthreads();  // all frag reads of prev iter done
        {
            const ubf16* ga = X  + (size_t)(mb + drow) * 1024 + kb + dcol;
            const ubf16* gb = Wt + (size_t)(nb + drow) * 1024 + kb + dcol;
            async_copy16(ga,               &As[w * 32][0]);
            async_copy16(ga + 16 * 1024,   &As[w * 32 + 16][0]);
            async_copy16(gb,               &Bs[w * 32][0]);
            async_copy16(gb + 16 * 1024,   &Bs[w * 32 + 16][0]);
        }
        __syncthreads();  // implies vmcnt drain: DMA complete + visible

        short8 af[4], bf[4];
#pragma unroll
        for (int i = 0; i < 4; ++i)
            af[i] = *(const short8*)(&As[wr + i * 16 + l15][quad * 8]);
#pragma unroll
        for (int j = 0; j < 4; ++j)
            bf[j] = *(const short8*)(&Bs[wc + j * 16 + l15][quad * 8]);
#pragma unroll
        for (int i = 0; i < 4; ++i)
#pragma unroll
            for (int j = 0; j < 4; ++j)
                acc[i][j] = __builtin_amdgcn_mfma_f32_16x16x32_bf16(
                    af[i], bf[j], acc[i][j], 0, 0, 0);
    }

    // epilogue
#pragma unroll
    for (int j = 0; j < 4; ++j) {
        const int c = nb + wc + j * 16 + l15;
        const float bx = bias[c];
#pragma unroll
        for (int i = 0; i < 4; ++i) {
            if (EPI == 2) {
                float* Y = (float*)Yv;
#pragma unroll
                for (int r = 0; r < 4; ++r) {
                    const int m = mb + wr + i * 16 + quad * 4 + r;
                    Y[(size_t)m * DM + c] = acc[i][j][r] + bx;
                }
            } else if (EPI == 0) {
                ubf16* Y = (ubf16*)Yv;
                const int h = c >> 6, d = c & 63;
#pragma unroll
                for (int r = 0; r < 4; ++r) {
                    const int m = mb + wr + i * 16 + quad * 4 + r;
                    const int n = m >> 11, t = m & 2047;
                    Y[(((size_t)(n * HEADS + h)) * T_S + t) * DK + d] =
                        f2bf(acc[i][j][r] + bx);
                }
            } else {  // EPI 1: V transposed [n][h][d][t]
                ubf16* Y = (ubf16*)Yv;
                const int h = c >> 6, d = c & 63;
                const int m0 = mb + wr + i * 16 + quad * 4;
                const int n = m0 >> 11, t0 = m0 & 2047;
                ushort4 o;
                o.x = f2bf(acc[i][j][0] + bx);
                o.y = f2bf(acc[i][j][1] + bx);
                o.z = f2bf(acc[i][j][2] + bx);
                o.w = f2bf(acc[i][j][3] + bx);
                *(ushort4*)(Y + (((size_t)(n * HEADS + h)) * DK + d) * T_S + t0) = o;
            }
        }
    }
}

// ---------------------------------------------------------------------------
// Flash attention, 32x32x16 MFMA, swapped operands, ZERO LDS / ZERO barriers.
//
// Block = 4 independent waves; wave w owns 32 q-rows [qb+32w, qb+32w+32).
// Per 64-key tile, per wave:
//   S^T = K Q^T   (A = K tile rows: m=key, k=d;  B = Q: n=q, k=d)
//     -> lane holds S^T[key][q] with q = lane&31 (lane-local softmax row!),
//        key = 32*kc + (r&3) + 8*(r>>2) + 4*(lane>>5).
//   p = exp(s/8) masked (causal+pad); lsum accumulates per lane (single q).
//   P -> bf16 A/B-frag layout via v_cvt_pk_bf16_f32 + v_permlane32_swap_b32
//     (keys 4hi+{0..3},8+4hi+{0..3},... -> keys hi*8+{0..7} per 16-chunk);
//     after pswap(w[0],w[2]), pswap(w[1],w[3]) the frag is w[0..3] in place.
//   O^T += V^T P^T  (A = V^T: m=d, k=key;  B = P^T: n=q, k=key)
//     -> lane holds O^T[d][q] with q = lane&31 (matches lsum, no broadcast).
// K/V/Q fragments are read straight from global (16 B/lane, L1/L2-resident;
// the 4 waves of a block share the same K/V tile through L1).  No __shared__,
// no __syncthreads => pure TLP latency hiding, no bank conflicts.
// ---------------------------------------------------------------------------
__global__ __launch_bounds__(256) void attn_mfma(
    const ubf16* __restrict__ Qh, const ubf16* __restrict__ Kh,
    const ubf16* __restrict__ Vt, const int* __restrict__ pm,
    ubf16* __restrict__ A)
{
    const int tid = threadIdx.x;
    const int w = tid >> 6, lid = tid & 63;
    const int l31 = lid & 31, hi = lid >> 5;
    const int qt = (int)gridDim.x - 1 - (int)blockIdx.x;   // big tiles first
    const int h = blockIdx.y, n = blockIdx.z;
    const int qb = qt * 128 + w * 32;      // this wave's q base
    const int qrow = qb + l31;             // this lane's q (S^T/O^T column)
    const size_t qkbase = ((size_t)(n * HEADS + h)) * T_S * DK;
    const size_t vbase  = ((size_t)(n * HEADS + h)) * DK * T_S;

    // Q fragments (B operand): qf[dk][j] = Q[qrow][dk*16 + hi*8 + j]
    short8 qf[4];
    {
        const ubf16* qp = Qh + qkbase + (size_t)qrow * DK + hi * 8;
#pragma unroll
        for (int dk = 0; dk < 4; ++dk)
            qf[dk] = *(const short8*)(qp + dk * 16);
    }

    floatx16 o0 = {}, o1 = {};   // O^T: d = dc*32 + (r&3)+8*(r>>2)+4*hi, q = l31
    float lsum = 0.f;
    const int ktmax = (qb + 31) >> 6;

    for (int kt = 0; kt <= ktmax; ++kt) {
        const int kb = kt * 64;
        const unsigned long long pmask =
            __ballot(pm[(size_t)n * T_S + kb + lid] != 0);

        // ---- S^T = K Q^T : 8 MFMAs over two 32-key chunks ----
        floatx16 s0 = {}, s1 = {};
        {
            const ubf16* kp = Kh + qkbase + (size_t)(kb + l31) * DK + hi * 8;
#pragma unroll
            for (int dk = 0; dk < 4; ++dk) {
                short8 kf0 = *(const short8*)(kp + dk * 16);
                short8 kf1 = *(const short8*)(kp + 32 * DK + dk * 16);
                s0 = __builtin_amdgcn_mfma_f32_32x32x16_bf16(kf0, qf[dk], s0, 0, 0, 0);
                s1 = __builtin_amdgcn_mfma_f32_32x32x16_bf16(kf1, qf[dk], s1, 0, 0, 0);
            }
        }

        // ---- softmax numerators (no-max; same numerics as incumbent) ----
        const bool fullk = (kb + 63) <= qb;          // tile fully causal-visible
        const bool nopad = (pmask == ~0ull);
        float p0[16], p1[16];
        if (fullk && nopad) {
#pragma unroll
            for (int r = 0; r < 16; ++r) {
                p0[r] = __expf(s0[r] * 0.125f);
                p1[r] = __expf(s1[r] * 0.125f);
                lsum += p0[r] + p1[r];
            }
        } else {
            const int qrel = qrow - kb;
#pragma unroll
            for (int r = 0; r < 16; ++r) {
                const int k0 = (r & 3) + 8 * (r >> 2) + 4 * hi;
                const int k1 = k0 + 32;
                const bool ok0 = (((pmask >> k0) & 1ull) != 0) && (k0 <= qrel);
                const bool ok1 = (((pmask >> k1) & 1ull) != 0) && (k1 <= qrel);
                p0[r] = ok0 ? __expf(s0[r] * 0.125f) : 0.f;
                p1[r] = ok1 ? __expf(s1[r] * 0.125f) : 0.f;
                lsum += p0[r] + p1[r];
            }
        }

        // ---- P -> bf16 fragments in-register (cvt_pk + permlane32_swap) ----
        unsigned wa[8], wb[8];
#pragma unroll
        for (int t = 0; t < 8; ++t) {
            wa[t] = cvtpk(p0[2 * t], p0[2 * t + 1]);
            wb[t] = cvtpk(p1[2 * t], p1[2 * t + 1]);
        }
        pswap(wa[0], wa[2]); pswap(wa[1], wa[3]);
        pswap(wa[4], wa[6]); pswap(wa[5], wa[7]);
        pswap(wb[0], wb[2]); pswap(wb[1], wb[3]);
        pswap(wb[4], wb[6]); pswap(wb[5], wb[7]);

        short8 pf[4];
        pf[0] = __builtin_bit_cast(short8, (uintx4){wa[0], wa[1], wa[2], wa[3]});
        pf[1] = __builtin_bit_cast(short8, (uintx4){wa[4], wa[5], wa[6], wa[7]});
        pf[2] = __builtin_bit_cast(short8, (uintx4){wb[0], wb[1], wb[2], wb[3]});
        pf[3] = __builtin_bit_cast(short8, (uintx4){wb[4], wb[5], wb[6], wb[7]});

        // ---- O^T += V^T P^T : 8 MFMAs ----
        {
            const ubf16* vp = Vt + vbase + (size_t)l31 * T_S + kb + hi * 8;
#pragma unroll
            for (int c = 0; c < 4; ++c) {
                short8 vf0 = *(const short8*)(vp + c * 16);
                short8 vf1 = *(const short8*)(vp + 32 * T_S + c * 16);
                o0 = __builtin_amdgcn_mfma_f32_32x32x16_bf16(vf0, pf[c], o0, 0, 0, 0);
                o1 = __builtin_amdgcn_mfma_f32_32x32x16_bf16(vf1, pf[c], o1, 0, 0, 0);
            }
        }
    }

    // ---- normalize + store: A [n][t][h*64+d] bf16 ----
    lsum += __shfl_xor(lsum, 32);
    const float inv = lsum > 0.f ? 1.0f / lsum : 0.f;

    ubf16* ap = A + ((size_t)n * T_S + qrow) * DM + h * DK;
#pragma unroll
    for (int g = 0; g < 4; ++g) {
        uint2 uv;
        uv.x = cvtpk(o0[4 * g + 0] * inv, o0[4 * g + 1] * inv);
        uv.y = cvtpk(o0[4 * g + 2] * inv, o0[4 * g + 3] * inv);
        *(uint2*)(ap + 8 * g + 4 * hi) = uv;
        uv.x = cvtpk(o1[4 * g + 0] * inv, o1[4 * g + 1] * inv);
        uv.y = cvtpk(o1[4 * g + 2] * inv, o1[4 * g + 3] * inv);
        *(uint2*)(ap + 32 + 8 * g + 4 * hi) = uv;
    }
}

// ---------------------------------------------------------------------------
extern "C" void kernel_launch(void* const* d_in, const int* in_sizes, int n_in,
                              void* d_out, int out_size, void* d_ws, size_t ws_size,
                              hipStream_t stream)
{
    const float* q  = (const float*)d_in[0];
    const float* k  = (const float*)d_in[1];
    const float* v  = (const float*)d_in[2];
    const int*   pm = (const int*)d_in[3];
    const float* Wq = (const float*)d_in[4];
    const float* bq = (const float*)d_in[5];
    const float* Wk = (const float*)d_in[6];
    const float* bk = (const float*)d_in[7];
    const float* Wv = (const float*)d_in[8];
    const float* bv = (const float*)d_in[9];
    const float* Wo = (const float*)d_in[10];
    const float* bo = (const float*)d_in[11];
    float* out = (float*)d_out;

    const size_t WT_E = (size_t)1024 * 1024;      // per-weight bf16 elems (2 MiB)
    const size_t HB_E = (size_t)8192 * 1024;      // batched per-tensor elems (16 MiB)
    const size_t PB_E = (size_t)2048 * 1024;      // per-batch elems (4 MiB)

    ubf16* WtQ = (ubf16*)d_ws;
    ubf16* WtK = WtQ + WT_E;
    ubf16* WtV = WtK + WT_E;
    ubf16* WtO = WtV + WT_E;
    ubf16* base = WtO + WT_E;

    dim3 blk(256);
    dim3 gtr(16, 16);
    wtrans<<<gtr, blk, 0, stream>>>(Wq, WtQ);
    wtrans<<<gtr, blk, 0, stream>>>(Wk, WtK);
    wtrans<<<gtr, blk, 0, stream>>>(Wv, WtV);
    wtrans<<<gtr, blk, 0, stream>>>(Wo, WtO);

    const size_t need_batched = (4 * WT_E + 4 * HB_E) * sizeof(ubf16);  // 72 MiB
    if (ws_size >= need_batched) {
        ubf16* Qh = base;
        ubf16* Kh = Qh + HB_E;
        ubf16* Vt = Kh + HB_E;
        ubf16* Aw = Vt + HB_E;       // doubles as the bf16-convert staging buf
        dim3 gg(64, 8);              // M=8192, N=1024, 128x128 tiles
        const int n8 = (int)(HB_E / 8);
        cvt_bf16<<<n8 / 256, blk, 0, stream>>>(q, Aw, n8);
        gemm_mfma<0><<<gg, blk, 0, stream>>>(Aw, WtQ, bq, Qh);
        cvt_bf16<<<n8 / 256, blk, 0, stream>>>(k, Aw, n8);
        gemm_mfma<0><<<gg, blk, 0, stream>>>(Aw, WtK, bk, Kh);
        cvt_bf16<<<n8 / 256, blk, 0, stream>>>(v, Aw, n8);
        gemm_mfma<1><<<gg, blk, 0, stream>>>(Aw, WtV, bv, Vt);
        dim3 ga(16, HEADS, N_B);     // 1024 blocks, 128 q-rows each
        attn_mfma<<<ga, blk, 0, stream>>>(Qh, Kh, Vt, pm, Aw);
        gemm_mfma<2><<<gg, blk, 0, stream>>>(Aw, WtO, bo, out);
    } else {
        // per-batch fallback (24 MiB workspace)
        ubf16* Qh = base;
        ubf16* Kh = Qh + PB_E;
        ubf16* Vt = Kh + PB_E;
        ubf16* Aw = Vt + PB_E;
        dim3 gg(16, 8);
        dim3 ga(16, HEADS, 1);
        const int n8 = (int)(PB_E / 8);
        for (int n = 0; n < N_B; ++n) {
            const size_t xoff = (size_t)n * T_S * DM;
            cvt_bf16<<<n8 / 256, blk, 0, stream>>>(q + xoff, Aw, n8);
            gemm_mfma<0><<<gg, blk, 0, stream>>>(Aw, WtQ, bq, Qh);
            cvt_bf16<<<n8 / 256, blk, 0, stream>>>(k + xoff, Aw, n8);
            gemm_mfma<0><<<gg, blk, 0, stream>>>(Aw, WtK, bk, Kh);
            cvt_bf16<<<n8 / 256, blk, 0, stream>>>(v + xoff, Aw, n8);
            gemm_mfma<1><<<gg, blk, 0, stream>>>(Aw, WtV, bv, Vt);
            attn_mfma<<<ga, blk, 0, stream>>>(Qh, Kh, Vt, pm + n * T_S, Aw);
            gemm_mfma<2><<<gg, blk, 0, stream>>>(Aw, WtO, bo, out + xoff);
        }
    }
}

// Round 2
// 379.638 us; speedup vs baseline: 1.3718x; 1.3718x over previous
//
#include <hip/hip_runtime.h>
#include <hip/hip_bf16.h>

// Problem constants (fixed by the reference)
#define N_B   4
#define T_S   2048
#define DM    1024
#define HEADS 16
#define DK    64

typedef unsigned short ubf16;  // raw bf16 bits
typedef __attribute__((ext_vector_type(8))) short short8;     // MFMA A/B frag (8 bf16)
typedef __attribute__((ext_vector_type(4))) float floatx4;    // 16x16 MFMA C/D frag
typedef __attribute__((ext_vector_type(16))) float floatx16;  // 32x32 MFMA C/D frag
typedef __attribute__((ext_vector_type(4))) unsigned uintx4;

__device__ __forceinline__ float bf2f(unsigned short u) {
    return __uint_as_float(((unsigned)u) << 16);
}
__device__ __forceinline__ unsigned short f2bf(float f) {
    unsigned u = __float_as_uint(f);
    u += 0x7fff + ((u >> 16) & 1);   // round-to-nearest-even
    return (unsigned short)(u >> 16);
}
// packed f32x2 -> bf16x2 (RNE), low word = a
__device__ __forceinline__ unsigned cvtpk(float a, float b) {
    unsigned r;
    asm("v_cvt_pk_bf16_f32 %0, %1, %2" : "=v"(r) : "v"(a), "v"(b));
    return r;
}
// swap a.hi32lanes <-> b.lo32lanes (gfx950)
__device__ __forceinline__ void pswap(unsigned& a, unsigned& b) {
    asm volatile("v_permlane32_swap_b32 %0, %1" : "+v"(a), "+v"(b));
}

// async global->LDS DMA, 16 B per lane; LDS dest = wave-uniform base + lane*16
__device__ __forceinline__ void async_copy16(const ubf16* g, ubf16* l) {
    __builtin_amdgcn_global_load_lds(
        (const __attribute__((address_space(1))) void*)g,
        (__attribute__((address_space(3))) void*)l, 16, 0, 0);
}

// ---------------------------------------------------------------------------
// fp32 -> bf16 bulk convert (8 elems/thread)
// ---------------------------------------------------------------------------
__global__ __launch_bounds__(256) void cvt_bf16(
    const float* __restrict__ X, ubf16* __restrict__ Y, int n8)
{
    const int i = blockIdx.x * 256 + threadIdx.x;
    if (i < n8) {
        const float4 a = ((const float4*)X)[2 * i];
        const float4 b = ((const float4*)X)[2 * i + 1];
        ushort4 o0, o1;
        o0.x = f2bf(a.x); o0.y = f2bf(a.y); o0.z = f2bf(a.z); o0.w = f2bf(a.w);
        o1.x = f2bf(b.x); o1.y = f2bf(b.y); o1.z = f2bf(b.z); o1.w = f2bf(b.w);
        ((ushort4*)Y)[2 * i]     = o0;
        ((ushort4*)Y)[2 * i + 1] = o1;
    }
}

// ---------------------------------------------------------------------------
// Weight transpose+convert: W fp32 [k][n] (1024x1024) -> Wt bf16 [n][k].
// ---------------------------------------------------------------------------
__global__ __launch_bounds__(256) void wtrans(
    const float* __restrict__ W, ubf16* __restrict__ Wt)
{
    __shared__ ubf16 T[64][72];
    const int tid = threadIdx.x;
    const int kb = blockIdx.x * 64, nb = blockIdx.y * 64;
    const int r = tid >> 2, cc = (tid & 3) * 16;
    const float* p = W + (size_t)(kb + r) * 1024 + nb + cc;
#pragma unroll
    for (int t = 0; t < 16; t += 4) {
        float4 x = *(const float4*)(p + t);
        T[r][cc + t + 0] = f2bf(x.x);
        T[r][cc + t + 1] = f2bf(x.y);
        T[r][cc + t + 2] = f2bf(x.z);
        T[r][cc + t + 3] = f2bf(x.w);
    }
    __syncthreads();
    ubf16 buf[16];
#pragma unroll
    for (int t = 0; t < 16; ++t) buf[t] = T[cc + t][r];   // transpose read
    ubf16* op = Wt + (size_t)(nb + r) * 1024 + kb + cc;
    *(uint4*)op       = *(uint4*)buf;
    *(uint4*)(op + 8) = *(uint4*)(buf + 8);
}

// ---------------------------------------------------------------------------
// MFMA GEMM (unchanged): Y = X[M,1024](bf16) @ Wt^T + bias.  Tile 128x128,
// BK=32, 4 waves (2x2), 64x64 C per wave, global_load_lds width=16 staging.
// EPI: 0 = bf16 heads [n][h][t][d]; 1 = bf16 V-transposed [n][h][d][t];
//      2 = fp32 row-major [m][1024].
// ---------------------------------------------------------------------------
template <int EPI>
__global__ __launch_bounds__(256) void gemm_mfma(
    const ubf16* __restrict__ X, const ubf16* __restrict__ Wt,
    const float* __restrict__ bias, void* __restrict__ Yv)
{
    __shared__ ubf16 As[128][32];  // [m][k], 64 B rows, unpadded (DMA layout)
    __shared__ ubf16 Bs[128][32];  // [n][k]

    const int tid = threadIdx.x;
    const int mb = blockIdx.x * 128, nb = blockIdx.y * 128;
    const int w = tid >> 6, lid = tid & 63, quad = lid >> 4, l15 = lid & 15;
    const int wr = (w >> 1) * 64, wc = (w & 1) * 64;

    // DMA source pattern: lane covers row w*32 + (lid>>2), col chunk (lid&3)*8
    const int drow = w * 32 + (lid >> 2);
    const int dcol = (lid & 3) * 8;

    floatx4 acc[4][4] = {};

    for (int kb = 0; kb < 1024; kb += 32) {
        if (kb) __syncthreads();  // all frag reads of prev iter done
        {
            const ubf16* ga = X  + (size_t)(mb + drow) * 1024 + kb + dcol;
            const ubf16* gb = Wt + (size_t)(nb + drow) * 1024 + kb + dcol;
            async_copy16(ga,               &As[w * 32][0]);
            async_copy16(ga + 16 * 1024,   &As[w * 32 + 16][0]);
            async_copy16(gb,               &Bs[w * 32][0]);
            async_copy16(gb + 16 * 1024,   &Bs[w * 32 + 16][0]);
        }
        __syncthreads();  // implies vmcnt drain: DMA complete + visible

        short8 af[4], bf[4];
#pragma unroll
        for (int i = 0; i < 4; ++i)
            af[i] = *(const short8*)(&As[wr + i * 16 + l15][quad * 8]);
#pragma unroll
        for (int j = 0; j < 4; ++j)
            bf[j] = *(const short8*)(&Bs[wc + j * 16 + l15][quad * 8]);
#pragma unroll
        for (int i = 0; i < 4; ++i)
#pragma unroll
            for (int j = 0; j < 4; ++j)
                acc[i][j] = __builtin_amdgcn_mfma_f32_16x16x32_bf16(
                    af[i], bf[j], acc[i][j], 0, 0, 0);
    }

    // epilogue
#pragma unroll
    for (int j = 0; j < 4; ++j) {
        const int c = nb + wc + j * 16 + l15;
        const float bx = bias[c];
#pragma unroll
        for (int i = 0; i < 4; ++i) {
            if (EPI == 2) {
                float* Y = (float*)Yv;
#pragma unroll
                for (int r = 0; r < 4; ++r) {
                    const int m = mb + wr + i * 16 + quad * 4 + r;
                    Y[(size_t)m * DM + c] = acc[i][j][r] + bx;
                }
            } else if (EPI == 0) {
                ubf16* Y = (ubf16*)Yv;
                const int h = c >> 6, d = c & 63;
#pragma unroll
                for (int r = 0; r < 4; ++r) {
                    const int m = mb + wr + i * 16 + quad * 4 + r;
                    const int n = m >> 11, t = m & 2047;
                    Y[(((size_t)(n * HEADS + h)) * T_S + t) * DK + d] =
                        f2bf(acc[i][j][r] + bx);
                }
            } else {  // EPI 1: V transposed [n][h][d][t]
                ubf16* Y = (ubf16*)Yv;
                const int h = c >> 6, d = c & 63;
                const int m0 = mb + wr + i * 16 + quad * 4;
                const int n = m0 >> 11, t0 = m0 & 2047;
                ushort4 o;
                o.x = f2bf(acc[i][j][0] + bx);
                o.y = f2bf(acc[i][j][1] + bx);
                o.z = f2bf(acc[i][j][2] + bx);
                o.w = f2bf(acc[i][j][3] + bx);
                *(ushort4*)(Y + (((size_t)(n * HEADS + h)) * DK + d) * T_S + t0) = o;
            }
        }
    }
}

// ---------------------------------------------------------------------------
// Flash attention, 32x32x16 MFMA, swapped operands, in-register P.
// LDS double-buffered K/V tiles staged via global_load_lds (2-phase pipeline).
//
// Block = 4 waves; wave w owns 32 q-rows [qt*128+32w, +32).  All waves share
// the block's K/V tiles (64 keys each) through LDS.
//
// LDS tile layout (both K [key][d] and V [d][key], 64x64 bf16, 128 B rows):
//   linear offset o maps to (row = o>>7, slot = (o>>4)&7); content at o is
//   global chunk  ch = slot ^ (row&7)  (inverse-swizzle applied on the GLOBAL
//   source address, since global_load_lds writes linearly: T21/m201 pattern).
//   Frag ds_read_b128 at  row*128 + ((cc ^ (row&7))*16)  -> 64 lanes cover 64
//   distinct 16B chunks uniformly over the 32 banks: conflict-free.
//
// Per 64-key tile, two 32-key halves (register-pressure split):
//   S^T = K Q^T (A=K: m=key, k=d; B=Q: n=q, k=d) -> lane owns q = lane&31.
//   p = exp(s/8) masked; lsum lane-local; P->bf16 frags via cvt_pk+permlane;
//   O^T += V^T P^T  (A=V^T: m=d, k=key).
// Pipeline per iteration: STAGE(next tile) ; compute(cur) ; __syncthreads()
//   (the barrier's implicit vmcnt(0) lands after ~700cy of compute -> the
//    global->LDS latency is hidden; guide T3 minimal 2-phase recipe).
// ---------------------------------------------------------------------------
__global__ __launch_bounds__(256, 4) void attn_mfma(
    const ubf16* __restrict__ Qh, const ubf16* __restrict__ Kh,
    const ubf16* __restrict__ Vt, const int* __restrict__ pm,
    ubf16* __restrict__ A)
{
    __shared__ ubf16 Ks[2][64 * 64];   // 8 KiB x2
    __shared__ ubf16 Vs[2][64 * 64];   // 8 KiB x2

    const int tid = threadIdx.x;
    const int w = tid >> 6, lid = tid & 63;
    const int l31 = lid & 31, hi = lid >> 5;
    const int qt = (int)gridDim.x - 1 - (int)blockIdx.x;   // big tiles first
    const int h = blockIdx.y, n = blockIdx.z;
    const int qb = qt * 128 + w * 32;      // this wave's q base
    const int qrow = qb + l31;             // this lane's q (S^T/O^T column)
    const size_t qkbase = ((size_t)(n * HEADS + h)) * T_S * DK;
    const size_t vbase  = ((size_t)(n * HEADS + h)) * DK * T_S;
    const int* pmn = pm + (size_t)n * T_S;

    // staging source pattern (per wave: calls c = 2w, 2w+1 for K and V):
    //   row = c*8 + (lid>>3), chunk = (lid&7) ^ ((lid>>3)&7)   [row&7 == (lid>>3)&7]
    const int srow = lid >> 3;                    // + c*8
    const int sch  = (lid & 7) ^ (srow & 7);      // pre-inverse-swizzled chunk

    // Q fragments (B operand): qf[dk][j] = Q[qrow][dk*16 + hi*8 + j]
    short8 qf[4];
    {
        const ubf16* qp = Qh + qkbase + (size_t)qrow * DK + hi * 8;
#pragma unroll
        for (int dk = 0; dk < 4; ++dk)
            qf[dk] = *(const short8*)(qp + dk * 16);
    }

    // frag-read swizzled offsets (loop-invariant): sw[j] = ((hi+2j) ^ (l31&7))*8
    int sw[4];
#pragma unroll
    for (int j = 0; j < 4; ++j) sw[j] = (((hi + 2 * j) ^ (l31 & 7)) * 8);

    const int ktm = 2 * qt + 1;            // block-uniform last tile

    // prologue: stage tile 0 into buf 0
    {
        const int c0 = 2 * w;
#pragma unroll
        for (int cc = 0; cc < 2; ++cc) {
            const int c = c0 + cc;
            const int row = c * 8 + srow;
            async_copy16(Kh + qkbase + (size_t)row * DK + sch * 8, &Ks[0][c * 512]);
            async_copy16(Vt + vbase + (size_t)row * T_S + sch * 8, &Vs[0][c * 512]);
        }
    }
    __syncthreads();   // implicit vmcnt(0): tile 0 resident

    floatx16 o0 = {}, o1 = {};   // O^T: d = dc*32 + (r&3)+8*(r>>2)+4*hi, q = l31
    float lsum = 0.f;

    for (int kt = 0; kt <= ktm; ++kt) {
        const int cur = kt & 1;
        const int kb = kt * 64;

        // stage next tile into the other buffer (latency hides under compute)
        if (kt < ktm) {
            const int kb2 = kb + 64;
            const int c0 = 2 * w;
#pragma unroll
            for (int cc = 0; cc < 2; ++cc) {
                const int c = c0 + cc;
                const int row = c * 8 + srow;
                async_copy16(Kh + qkbase + (size_t)(kb2 + row) * DK + sch * 8,
                             &Ks[cur ^ 1][c * 512]);
                async_copy16(Vt + vbase + (size_t)row * T_S + kb2 + sch * 8,
                             &Vs[cur ^ 1][c * 512]);
            }
        }

        if (kb <= qb + 31) {   // wave-uniform: tile has visible keys
            const unsigned long long pmask = __ballot(pmn[kb + lid] != 0);
            const ubf16* Kr0 = &Ks[cur][l31 * 64];
            const ubf16* Kr1 = Kr0 + 32 * 64;
            const ubf16* Vr0 = &Vs[cur][l31 * 64];
            const ubf16* Vr1 = Vr0 + 32 * 64;
            const int qrel = qrow - kb;

            // ---------- half A: keys kb .. kb+31 ----------
            {
                floatx16 s = {};
#pragma unroll
                for (int dk = 0; dk < 4; ++dk) {
                    short8 kf = *(const short8*)(Kr0 + sw[dk]);
                    s = __builtin_amdgcn_mfma_f32_32x32x16_bf16(kf, qf[dk], s, 0, 0, 0);
                }
                float p[16];
                const bool full = (kb + 31 <= qb) &&
                                  ((unsigned)pmask == 0xffffffffu);
                if (full) {
#pragma unroll
                    for (int r = 0; r < 16; ++r) {
                        p[r] = __expf(s[r] * 0.125f);
                        lsum += p[r];
                    }
                } else {
#pragma unroll
                    for (int r = 0; r < 16; ++r) {
                        const int k0 = (r & 3) + 8 * (r >> 2) + 4 * hi;
                        const bool ok = (((pmask >> k0) & 1ull) != 0) && (k0 <= qrel);
                        p[r] = ok ? __expf(s[r] * 0.125f) : 0.f;
                        lsum += p[r];
                    }
                }
                unsigned wa[8];
#pragma unroll
                for (int t = 0; t < 8; ++t) wa[t] = cvtpk(p[2 * t], p[2 * t + 1]);
                pswap(wa[0], wa[2]); pswap(wa[1], wa[3]);
                pswap(wa[4], wa[6]); pswap(wa[5], wa[7]);
                short8 pf0 = __builtin_bit_cast(short8, (uintx4){wa[0], wa[1], wa[2], wa[3]});
                short8 pf1 = __builtin_bit_cast(short8, (uintx4){wa[4], wa[5], wa[6], wa[7]});
                {
                    short8 vf0 = *(const short8*)(Vr0 + sw[0]);
                    short8 vf1 = *(const short8*)(Vr1 + sw[0]);
                    o0 = __builtin_amdgcn_mfma_f32_32x32x16_bf16(vf0, pf0, o0, 0, 0, 0);
                    o1 = __builtin_amdgcn_mfma_f32_32x32x16_bf16(vf1, pf0, o1, 0, 0, 0);
                    vf0 = *(const short8*)(Vr0 + sw[1]);
                    vf1 = *(const short8*)(Vr1 + sw[1]);
                    o0 = __builtin_amdgcn_mfma_f32_32x32x16_bf16(vf0, pf1, o0, 0, 0, 0);
                    o1 = __builtin_amdgcn_mfma_f32_32x32x16_bf16(vf1, pf1, o1, 0, 0, 0);
                }
            }

            // ---------- half B: keys kb+32 .. kb+63 ----------
            if (kb + 32 <= qb + 31) {
                floatx16 s = {};
#pragma unroll
                for (int dk = 0; dk < 4; ++dk) {
                    short8 kf = *(const short8*)(Kr1 + sw[dk]);
                    s = __builtin_amdgcn_mfma_f32_32x32x16_bf16(kf, qf[dk], s, 0, 0, 0);
                }
                float p[16];
                const bool full = (kb + 63 <= qb) &&
                                  ((unsigned)(pmask >> 32) == 0xffffffffu);
                if (full) {
#pragma unroll
                    for (int r = 0; r < 16; ++r) {
                        p[r] = __expf(s[r] * 0.125f);
                        lsum += p[r];
                    }
                } else {
#pragma unroll
                    for (int r = 0; r < 16; ++r) {
                        const int k1 = 32 + (r & 3) + 8 * (r >> 2) + 4 * hi;
                        const bool ok = (((pmask >> k1) & 1ull) != 0) && (k1 <= qrel);
                        p[r] = ok ? __expf(s[r] * 0.125f) : 0.f;
                        lsum += p[r];
                    }
                }
                unsigned wb[8];
#pragma unroll
                for (int t = 0; t < 8; ++t) wb[t] = cvtpk(p[2 * t], p[2 * t + 1]);
                pswap(wb[0], wb[2]); pswap(wb[1], wb[3]);
                pswap(wb[4], wb[6]); pswap(wb[5], wb[7]);
                short8 pf2 = __builtin_bit_cast(short8, (uintx4){wb[0], wb[1], wb[2], wb[3]});
                short8 pf3 = __builtin_bit_cast(short8, (uintx4){wb[4], wb[5], wb[6], wb[7]});
                {
                    short8 vf0 = *(const short8*)(Vr0 + sw[2]);
                    short8 vf1 = *(const short8*)(Vr1 + sw[2]);
                    o0 = __builtin_amdgcn_mfma_f32_32x32x16_bf16(vf0, pf2, o0, 0, 0, 0);
                    o1 = __builtin_amdgcn_mfma_f32_32x32x16_bf16(vf1, pf2, o1, 0, 0, 0);
                    vf0 = *(const short8*)(Vr0 + sw[3]);
                    vf1 = *(const short8*)(Vr1 + sw[3]);
                    o0 = __builtin_amdgcn_mfma_f32_32x32x16_bf16(vf0, pf3, o0, 0, 0, 0);
                    o1 = __builtin_amdgcn_mfma_f32_32x32x16_bf16(vf1, pf3, o1, 0, 0, 0);
                }
            }
        }
        __syncthreads();   // all reads of cur done; next-tile DMA drained
    }

    // ---- normalize + store: A [n][t][h*64+d] bf16 ----
    lsum += __shfl_xor(lsum, 32);
    const float inv = lsum > 0.f ? 1.0f / lsum : 0.f;

    ubf16* ap = A + ((size_t)n * T_S + qrow) * DM + h * DK;
#pragma unroll
    for (int g = 0; g < 4; ++g) {
        uint2 uv;
        uv.x = cvtpk(o0[4 * g + 0] * inv, o0[4 * g + 1] * inv);
        uv.y = cvtpk(o0[4 * g + 2] * inv, o0[4 * g + 3] * inv);
        *(uint2*)(ap + 8 * g + 4 * hi) = uv;
        uv.x = cvtpk(o1[4 * g + 0] * inv, o1[4 * g + 1] * inv);
        uv.y = cvtpk(o1[4 * g + 2] * inv, o1[4 * g + 3] * inv);
        *(uint2*)(ap + 32 + 8 * g + 4 * hi) = uv;
    }
}

// ---------------------------------------------------------------------------
extern "C" void kernel_launch(void* const* d_in, const int* in_sizes, int n_in,
                              void* d_out, int out_size, void* d_ws, size_t ws_size,
                              hipStream_t stream)
{
    const float* q  = (const float*)d_in[0];
    const float* k  = (const float*)d_in[1];
    const float* v  = (const float*)d_in[2];
    const int*   pm = (const int*)d_in[3];
    const float* Wq = (const float*)d_in[4];
    const float* bq = (const float*)d_in[5];
    const float* Wk = (const float*)d_in[6];
    const float* bk = (const float*)d_in[7];
    const float* Wv = (const float*)d_in[8];
    const float* bv = (const float*)d_in[9];
    const float* Wo = (const float*)d_in[10];
    const float* bo = (const float*)d_in[11];
    float* out = (float*)d_out;

    const size_t WT_E = (size_t)1024 * 1024;      // per-weight bf16 elems (2 MiB)
    const size_t HB_E = (size_t)8192 * 1024;      // batched per-tensor elems (16 MiB)
    const size_t PB_E = (size_t)2048 * 1024;      // per-batch elems (4 MiB)

    ubf16* WtQ = (ubf16*)d_ws;
    ubf16* WtK = WtQ + WT_E;
    ubf16* WtV = WtK + WT_E;
    ubf16* WtO = WtV + WT_E;
    ubf16* base = WtO + WT_E;

    dim3 blk(256);
    dim3 gtr(16, 16);
    wtrans<<<gtr, blk, 0, stream>>>(Wq, WtQ);
    wtrans<<<gtr, blk, 0, stream>>>(Wk, WtK);
    wtrans<<<gtr, blk, 0, stream>>>(Wv, WtV);
    wtrans<<<gtr, blk, 0, stream>>>(Wo, WtO);

    const size_t need_batched = (4 * WT_E + 4 * HB_E) * sizeof(ubf16);  // 72 MiB
    if (ws_size >= need_batched) {
        ubf16* Qh = base;
        ubf16* Kh = Qh + HB_E;
        ubf16* Vt = Kh + HB_E;
        ubf16* Aw = Vt + HB_E;       // doubles as the bf16-convert staging buf
        dim3 gg(64, 8);              // M=8192, N=1024, 128x128 tiles
        const int n8 = (int)(HB_E / 8);
        cvt_bf16<<<n8 / 256, blk, 0, stream>>>(q, Aw, n8);
        gemm_mfma<0><<<gg, blk, 0, stream>>>(Aw, WtQ, bq, Qh);
        cvt_bf16<<<n8 / 256, blk, 0, stream>>>(k, Aw, n8);
        gemm_mfma<0><<<gg, blk, 0, stream>>>(Aw, WtK, bk, Kh);
        cvt_bf16<<<n8 / 256, blk, 0, stream>>>(v, Aw, n8);
        gemm_mfma<1><<<gg, blk, 0, stream>>>(Aw, WtV, bv, Vt);
        dim3 ga(16, HEADS, N_B);     // 1024 blocks, 128 q-rows each
        attn_mfma<<<ga, blk, 0, stream>>>(Qh, Kh, Vt, pm, Aw);
        gemm_mfma<2><<<gg, blk, 0, stream>>>(Aw, WtO, bo, out);
    } else {
        // per-batch fallback (24 MiB workspace)
        ubf16* Qh = base;
        ubf16* Kh = Qh + PB_E;
        ubf16* Vt = Kh + PB_E;
        ubf16* Aw = Vt + PB_E;
        dim3 gg(16, 8);
        dim3 ga(16, HEADS, 1);
        const int n8 = (int)(PB_E / 8);
        for (int n = 0; n < N_B; ++n) {
            const size_t xoff = (size_t)n * T_S * DM;
            cvt_bf16<<<n8 / 256, blk, 0, stream>>>(q + xoff, Aw, n8);
            gemm_mfma<0><<<gg, blk, 0, stream>>>(Aw, WtQ, bq, Qh);
            cvt_bf16<<<n8 / 256, blk, 0, stream>>>(k + xoff, Aw, n8);
            gemm_mfma<0><<<gg, blk, 0, stream>>>(Aw, WtK, bk, Kh);
            cvt_bf16<<<n8 / 256, blk, 0, stream>>>(v + xoff, Aw, n8);
            gemm_mfma<1><<<gg, blk, 0, stream>>>(Aw, WtV, bv, Vt);
            attn_mfma<<<ga, blk, 0, stream>>>(Qh, Kh, Vt, pm + n * T_S, Aw);
            gemm_mfma<2><<<gg, blk, 0, stream>>>(Aw, WtO, bo, out + xoff);
        }
    }
}

// Round 3
// 365.800 us; speedup vs baseline: 1.4237x; 1.0378x over previous
//
#include <hip/hip_runtime.h>
#include <hip/hip_bf16.h>

// Problem constants (fixed by the reference)
#define N_B   4
#define T_S   2048
#define DM    1024
#define HEADS 16
#define DK    64

typedef unsigned short ubf16;  // raw bf16 bits
typedef __attribute__((ext_vector_type(8))) short short8;     // MFMA A/B frag (8 bf16)
typedef __attribute__((ext_vector_type(4))) float floatx4;    // 16x16 MFMA C/D frag
typedef __attribute__((ext_vector_type(16))) float floatx16;  // 32x32 MFMA C/D frag
typedef __attribute__((ext_vector_type(4))) unsigned uintx4;

__device__ __forceinline__ float bf2f(unsigned short u) {
    return __uint_as_float(((unsigned)u) << 16);
}
__device__ __forceinline__ unsigned short f2bf(float f) {
    unsigned u = __float_as_uint(f);
    u += 0x7fff + ((u >> 16) & 1);   // round-to-nearest-even
    return (unsigned short)(u >> 16);
}
// packed f32x2 -> bf16x2 (RNE), low word = a
__device__ __forceinline__ unsigned cvtpk(float a, float b) {
    unsigned r;
    asm("v_cvt_pk_bf16_f32 %0, %1, %2" : "=v"(r) : "v"(a), "v"(b));
    return r;
}
// swap a.hi32lanes <-> b.lo32lanes (gfx950)
__device__ __forceinline__ void pswap(unsigned& a, unsigned& b) {
    asm volatile("v_permlane32_swap_b32 %0, %1" : "+v"(a), "+v"(b));
}

// async global->LDS DMA, 16 B per lane; LDS dest = wave-uniform base + lane*16
__device__ __forceinline__ void async_copy16(const ubf16* g, ubf16* l) {
    __builtin_amdgcn_global_load_lds(
        (const __attribute__((address_space(1))) void*)g,
        (__attribute__((address_space(3))) void*)l, 16, 0, 0);
}

// ---------------------------------------------------------------------------
// fp32 -> bf16 bulk convert (8 elems/thread)
// ---------------------------------------------------------------------------
__global__ __launch_bounds__(256) void cvt_bf16(
    const float* __restrict__ X, ubf16* __restrict__ Y, int n8)
{
    const int i = blockIdx.x * 256 + threadIdx.x;
    if (i < n8) {
        const float4 a = ((const float4*)X)[2 * i];
        const float4 b = ((const float4*)X)[2 * i + 1];
        ushort4 o0, o1;
        o0.x = f2bf(a.x); o0.y = f2bf(a.y); o0.z = f2bf(a.z); o0.w = f2bf(a.w);
        o1.x = f2bf(b.x); o1.y = f2bf(b.y); o1.z = f2bf(b.z); o1.w = f2bf(b.w);
        ((ushort4*)Y)[2 * i]     = o0;
        ((ushort4*)Y)[2 * i + 1] = o1;
    }
}

// ---------------------------------------------------------------------------
// Weight transpose+convert: W fp32 [k][n] (1024x1024) -> Wt bf16 [n][k].
// ---------------------------------------------------------------------------
__global__ __launch_bounds__(256) void wtrans(
    const float* __restrict__ W, ubf16* __restrict__ Wt)
{
    __shared__ ubf16 T[64][72];
    const int tid = threadIdx.x;
    const int kb = blockIdx.x * 64, nb = blockIdx.y * 64;
    const int r = tid >> 2, cc = (tid & 3) * 16;
    const float* p = W + (size_t)(kb + r) * 1024 + nb + cc;
#pragma unroll
    for (int t = 0; t < 16; t += 4) {
        float4 x = *(const float4*)(p + t);
        T[r][cc + t + 0] = f2bf(x.x);
        T[r][cc + t + 1] = f2bf(x.y);
        T[r][cc + t + 2] = f2bf(x.z);
        T[r][cc + t + 3] = f2bf(x.w);
    }
    __syncthreads();
    ubf16 buf[16];
#pragma unroll
    for (int t = 0; t < 16; ++t) buf[t] = T[cc + t][r];   // transpose read
    ubf16* op = Wt + (size_t)(nb + r) * 1024 + kb + cc;
    *(uint4*)op       = *(uint4*)buf;
    *(uint4*)(op + 8) = *(uint4*)(buf + 8);
}

// ---------------------------------------------------------------------------
// MFMA GEMM: Y = X[M,1024](bf16) @ Wt^T + bias.  Tile 128x128, BK=64,
// 4 waves (2x2), 64x64 C per wave.  DOUBLE-BUFFERED 2-phase pipeline:
// prologue stages tile 0; each iteration issues DMA for tile t+1 into the
// other buffer, computes tile t, then one __syncthreads() (its implicit
// vmcnt(0) lands after ~600cy of compute -> DMA latency hidden; T3 recipe).
//
// LDS rows are 128 B (8 chunks of 16 B) -> XOR-swizzle needed (T2/T21):
// DMA writes linearly, so the GLOBAL source is pre-inverse-swizzled
// (chunk = slot ^ (row&7)); frag ds_read_b128 applies the same XOR ->
// each of the 8 bank-quartets serves exactly 8 lanes: conflict-free.
//
// Fragment layouts (mfma_f32_16x16x32_bf16, m89-verified):
//   A: m=lane&15, k=quad*8+j ; B: n=lane&15, k=quad*8+j
//   C: col=lane&15, row=quad*4+reg
// EPI: 0 = bf16 heads [n][h][t][d]; 1 = bf16 V-transposed [n][h][d][t];
//      2 = fp32 row-major [m][1024].
// ---------------------------------------------------------------------------
template <int EPI>
__global__ __launch_bounds__(256) void gemm_mfma(
    const ubf16* __restrict__ X, const ubf16* __restrict__ Wt,
    const float* __restrict__ bias, void* __restrict__ Yv)
{
    __shared__ ubf16 As[2][128][64];  // 16 KiB per buf
    __shared__ ubf16 Bs[2][128][64];

    const int tid = threadIdx.x;
    const int mb = blockIdx.x * 128, nb = blockIdx.y * 128;
    const int w = tid >> 6, lid = tid & 63, quad = lid >> 4, l15 = lid & 15;
    const int wr = (w >> 1) * 64, wc = (w & 1) * 64;

    // DMA pattern: call c covers rows w*32+c*8 .. +8; lane -> row base+(lid>>3),
    // LDS slot lid&7; source chunk = slot ^ (row&7)  [row&7 == lid>>3]
    const int srow = lid >> 3;                 // 0..7
    const int sch  = (lid & 7) ^ srow;         // pre-inverse-swizzled chunk
    const ubf16* gA = X  + (size_t)(mb + w * 32 + srow) * 1024 + sch * 8;
    const ubf16* gB = Wt + (size_t)(nb + w * 32 + srow) * 1024 + sch * 8;

    // frag-read swizzled chunk offsets (elements): ((ks*4+quad) ^ (l15&7)) * 8
    const int m7 = l15 & 7;
    const int sw0 = ((0 + quad) ^ m7) * 8;     // ks = 0
    const int sw1 = ((4 + quad) ^ m7) * 8;     // ks = 1

    floatx4 acc[4][4] = {};

#define GEMM_STAGE(KB, BUF)                                                  \
    {                                                                        \
        _Pragma("unroll")                                                    \
        for (int c = 0; c < 4; ++c) {                                        \
            async_copy16(gA + (size_t)(c * 8) * 1024 + (KB),                 \
                         &As[BUF][w * 32 + c * 8][0]);                       \
            async_copy16(gB + (size_t)(c * 8) * 1024 + (KB),                 \
                         &Bs[BUF][w * 32 + c * 8][0]);                       \
        }                                                                    \
    }

    GEMM_STAGE(0, 0);
    __syncthreads();   // implicit vmcnt(0): tile 0 resident

    for (int t = 0; t < 16; ++t) {
        const int cur = t & 1;
        if (t < 15) GEMM_STAGE((t + 1) * 64, cur ^ 1);

#pragma unroll
        for (int ks = 0; ks < 2; ++ks) {
            const int sw = ks ? sw1 : sw0;
            short8 af[4], bf[4];
#pragma unroll
            for (int i = 0; i < 4; ++i)
                af[i] = *(const short8*)(&As[cur][wr + i * 16 + l15][0] + sw);
#pragma unroll
            for (int j = 0; j < 4; ++j)
                bf[j] = *(const short8*)(&Bs[cur][wc + j * 16 + l15][0] + sw);
#pragma unroll
            for (int i = 0; i < 4; ++i)
#pragma unroll
                for (int j = 0; j < 4; ++j)
                    acc[i][j] = __builtin_amdgcn_mfma_f32_16x16x32_bf16(
                        af[i], bf[j], acc[i][j], 0, 0, 0);
        }
        __syncthreads();   // cur reads done; next-tile DMA drained
    }
#undef GEMM_STAGE

    // epilogue
#pragma unroll
    for (int j = 0; j < 4; ++j) {
        const int c = nb + wc + j * 16 + l15;
        const float bx = bias[c];
#pragma unroll
        for (int i = 0; i < 4; ++i) {
            if (EPI == 2) {
                float* Y = (float*)Yv;
#pragma unroll
                for (int r = 0; r < 4; ++r) {
                    const int m = mb + wr + i * 16 + quad * 4 + r;
                    Y[(size_t)m * DM + c] = acc[i][j][r] + bx;
                }
            } else if (EPI == 0) {
                ubf16* Y = (ubf16*)Yv;
                const int h = c >> 6, d = c & 63;
#pragma unroll
                for (int r = 0; r < 4; ++r) {
                    const int m = mb + wr + i * 16 + quad * 4 + r;
                    const int n = m >> 11, t = m & 2047;
                    Y[(((size_t)(n * HEADS + h)) * T_S + t) * DK + d] =
                        f2bf(acc[i][j][r] + bx);
                }
            } else {  // EPI 1: V transposed [n][h][d][t]
                ubf16* Y = (ubf16*)Yv;
                const int h = c >> 6, d = c & 63;
                const int m0 = mb + wr + i * 16 + quad * 4;
                const int n = m0 >> 11, t0 = m0 & 2047;
                ushort4 o;
                o.x = f2bf(acc[i][j][0] + bx);
                o.y = f2bf(acc[i][j][1] + bx);
                o.z = f2bf(acc[i][j][2] + bx);
                o.w = f2bf(acc[i][j][3] + bx);
                *(ushort4*)(Y + (((size_t)(n * HEADS + h)) * DK + d) * T_S + t0) = o;
            }
        }
    }
}

// ---------------------------------------------------------------------------
// Flash attention, 32x32x16 MFMA, swapped operands, in-register P,
// LDS double-buffered K/V staged via global_load_lds (2-phase pipeline).
//
// Causal load balance: gridDim.x = 8; block bx processes q-tile (15-bx) then
// q-tile bx sequentially -> uniform 34 key-tiles per block, 512 blocks all
// resident to the finish (fixes the 19.5%-occupancy decaying tail of the
// 1-tile-per-block version).
//
// Per pass: wave w owns 32 q-rows of the 128-row q-tile.  LDS tiles are
// 64x64 bf16, 128 B rows, XOR-swizzled via pre-swizzled global source.
// S^T = K Q^T (lane owns q = lane&31); p = exp(s/8) masked; P->bf16 frags
// via cvt_pk+permlane32_swap; O^T += V^T P^T.
// ---------------------------------------------------------------------------
__global__ __launch_bounds__(256, 4) void attn_mfma(
    const ubf16* __restrict__ Qh, const ubf16* __restrict__ Kh,
    const ubf16* __restrict__ Vt, const int* __restrict__ pm,
    ubf16* __restrict__ A)
{
    __shared__ ubf16 Ks[2][64 * 64];   // 8 KiB x2
    __shared__ ubf16 Vs[2][64 * 64];   // 8 KiB x2

    const int tid = threadIdx.x;
    const int w = tid >> 6, lid = tid & 63;
    const int l31 = lid & 31, hi = lid >> 5;
    const int bx = (int)blockIdx.x;                 // 0..7
    const int h = blockIdx.y, n = blockIdx.z;
    const size_t qkbase = ((size_t)(n * HEADS + h)) * T_S * DK;
    const size_t vbase  = ((size_t)(n * HEADS + h)) * DK * T_S;
    const int* pmn = pm + (size_t)n * T_S;

    // staging source pattern (per wave: calls c = 2w, 2w+1 for K and V):
    //   row = c*8 + (lid>>3), chunk = (lid&7) ^ ((lid>>3)&7)
    const int srow = lid >> 3;                    // + c*8
    const int sch  = (lid & 7) ^ (srow & 7);      // pre-inverse-swizzled chunk

    // frag-read swizzled offsets (loop-invariant): sw[j] = ((hi+2j) ^ (l31&7))*8
    int sw[4];
#pragma unroll
    for (int j = 0; j < 4; ++j) sw[j] = (((hi + 2 * j) ^ (l31 & 7)) * 8);

    for (int pass = 0; pass < 2; ++pass) {
        const int qt = pass == 0 ? (15 - bx) : bx;   // big pass first
        const int qb = qt * 128 + w * 32;            // this wave's q base
        const int qrow = qb + l31;                   // this lane's q

        // Q fragments (B operand): qf[dk][j] = Q[qrow][dk*16 + hi*8 + j]
        short8 qf[4];
        {
            const ubf16* qp = Qh + qkbase + (size_t)qrow * DK + hi * 8;
#pragma unroll
            for (int dk = 0; dk < 4; ++dk)
                qf[dk] = *(const short8*)(qp + dk * 16);
        }

        const int ktm = 2 * qt + 1;            // block-uniform last tile

        // prologue: stage tile 0 into buf 0
        {
            const int c0 = 2 * w;
#pragma unroll
            for (int cc = 0; cc < 2; ++cc) {
                const int c = c0 + cc;
                const int row = c * 8 + srow;
                async_copy16(Kh + qkbase + (size_t)row * DK + sch * 8, &Ks[0][c * 512]);
                async_copy16(Vt + vbase + (size_t)row * T_S + sch * 8, &Vs[0][c * 512]);
            }
        }
        __syncthreads();   // implicit vmcnt(0): tile 0 resident

        floatx16 o0 = {}, o1 = {};   // O^T: d = dc*32+(r&3)+8*(r>>2)+4*hi, q = l31
        float lsum = 0.f;

        for (int kt = 0; kt <= ktm; ++kt) {
            const int cur = kt & 1;
            const int kb = kt * 64;

            // stage next tile into the other buffer (hides under compute)
            if (kt < ktm) {
                const int kb2 = kb + 64;
                const int c0 = 2 * w;
#pragma unroll
                for (int cc = 0; cc < 2; ++cc) {
                    const int c = c0 + cc;
                    const int row = c * 8 + srow;
                    async_copy16(Kh + qkbase + (size_t)(kb2 + row) * DK + sch * 8,
                                 &Ks[cur ^ 1][c * 512]);
                    async_copy16(Vt + vbase + (size_t)row * T_S + kb2 + sch * 8,
                                 &Vs[cur ^ 1][c * 512]);
                }
            }

            if (kb <= qb + 31) {   // wave-uniform: tile has visible keys
                const unsigned long long pmask = __ballot(pmn[kb + lid] != 0);
                const ubf16* Kr0 = &Ks[cur][l31 * 64];
                const ubf16* Kr1 = Kr0 + 32 * 64;
                const ubf16* Vr0 = &Vs[cur][l31 * 64];
                const ubf16* Vr1 = Vr0 + 32 * 64;
                const int qrel = qrow - kb;

                // ---------- half A: keys kb .. kb+31 ----------
                {
                    floatx16 s = {};
#pragma unroll
                    for (int dk = 0; dk < 4; ++dk) {
                        short8 kf = *(const short8*)(Kr0 + sw[dk]);
                        s = __builtin_amdgcn_mfma_f32_32x32x16_bf16(kf, qf[dk], s, 0, 0, 0);
                    }
                    float p[16];
                    const bool full = (kb + 31 <= qb) &&
                                      ((unsigned)pmask == 0xffffffffu);
                    if (full) {
#pragma unroll
                        for (int r = 0; r < 16; ++r) {
                            p[r] = __expf(s[r] * 0.125f);
                            lsum += p[r];
                        }
                    } else {
#pragma unroll
                        for (int r = 0; r < 16; ++r) {
                            const int k0 = (r & 3) + 8 * (r >> 2) + 4 * hi;
                            const bool ok = (((pmask >> k0) & 1ull) != 0) && (k0 <= qrel);
                            p[r] = ok ? __expf(s[r] * 0.125f) : 0.f;
                            lsum += p[r];
                        }
                    }
                    unsigned wa[8];
#pragma unroll
                    for (int t = 0; t < 8; ++t) wa[t] = cvtpk(p[2 * t], p[2 * t + 1]);
                    pswap(wa[0], wa[2]); pswap(wa[1], wa[3]);
                    pswap(wa[4], wa[6]); pswap(wa[5], wa[7]);
                    short8 pf0 = __builtin_bit_cast(short8, (uintx4){wa[0], wa[1], wa[2], wa[3]});
                    short8 pf1 = __builtin_bit_cast(short8, (uintx4){wa[4], wa[5], wa[6], wa[7]});
                    {
                        short8 vf0 = *(const short8*)(Vr0 + sw[0]);
                        short8 vf1 = *(const short8*)(Vr1 + sw[0]);
                        o0 = __builtin_amdgcn_mfma_f32_32x32x16_bf16(vf0, pf0, o0, 0, 0, 0);
                        o1 = __builtin_amdgcn_mfma_f32_32x32x16_bf16(vf1, pf0, o1, 0, 0, 0);
                        vf0 = *(const short8*)(Vr0 + sw[1]);
                        vf1 = *(const short8*)(Vr1 + sw[1]);
                        o0 = __builtin_amdgcn_mfma_f32_32x32x16_bf16(vf0, pf1, o0, 0, 0, 0);
                        o1 = __builtin_amdgcn_mfma_f32_32x32x16_bf16(vf1, pf1, o1, 0, 0, 0);
                    }
                }

                // ---------- half B: keys kb+32 .. kb+63 ----------
                if (kb + 32 <= qb + 31) {
                    floatx16 s = {};
#pragma unroll
                    for (int dk = 0; dk < 4; ++dk) {
                        short8 kf = *(const short8*)(Kr1 + sw[dk]);
                        s = __builtin_amdgcn_mfma_f32_32x32x16_bf16(kf, qf[dk], s, 0, 0, 0);
                    }
                    float p[16];
                    const bool full = (kb + 63 <= qb) &&
                                      ((unsigned)(pmask >> 32) == 0xffffffffu);
                    if (full) {
#pragma unroll
                        for (int r = 0; r < 16; ++r) {
                            p[r] = __expf(s[r] * 0.125f);
                            lsum += p[r];
                        }
                    } else {
#pragma unroll
                        for (int r = 0; r < 16; ++r) {
                            const int k1 = 32 + (r & 3) + 8 * (r >> 2) + 4 * hi;
                            const bool ok = (((pmask >> k1) & 1ull) != 0) && (k1 <= qrel);
                            p[r] = ok ? __expf(s[r] * 0.125f) : 0.f;
                            lsum += p[r];
                        }
                    }
                    unsigned wb[8];
#pragma unroll
                    for (int t = 0; t < 8; ++t) wb[t] = cvtpk(p[2 * t], p[2 * t + 1]);
                    pswap(wb[0], wb[2]); pswap(wb[1], wb[3]);
                    pswap(wb[4], wb[6]); pswap(wb[5], wb[7]);
                    short8 pf2 = __builtin_bit_cast(short8, (uintx4){wb[0], wb[1], wb[2], wb[3]});
                    short8 pf3 = __builtin_bit_cast(short8, (uintx4){wb[4], wb[5], wb[6], wb[7]});
                    {
                        short8 vf0 = *(const short8*)(Vr0 + sw[2]);
                        short8 vf1 = *(const short8*)(Vr1 + sw[2]);
                        o0 = __builtin_amdgcn_mfma_f32_32x32x16_bf16(vf0, pf2, o0, 0, 0, 0);
                        o1 = __builtin_amdgcn_mfma_f32_32x32x16_bf16(vf1, pf2, o1, 0, 0, 0);
                        vf0 = *(const short8*)(Vr0 + sw[3]);
                        vf1 = *(const short8*)(Vr1 + sw[3]);
                        o0 = __builtin_amdgcn_mfma_f32_32x32x16_bf16(vf0, pf3, o0, 0, 0, 0);
                        o1 = __builtin_amdgcn_mfma_f32_32x32x16_bf16(vf1, pf3, o1, 0, 0, 0);
                    }
                }
            }
            __syncthreads();   // cur reads done; next-tile DMA drained
        }

        // ---- normalize + store: A [n][t][h*64+d] bf16 ----
        lsum += __shfl_xor(lsum, 32);
        const float inv = lsum > 0.f ? 1.0f / lsum : 0.f;

        ubf16* ap = A + ((size_t)n * T_S + qrow) * DM + h * DK;
#pragma unroll
        for (int g = 0; g < 4; ++g) {
            uint2 uv;
            uv.x = cvtpk(o0[4 * g + 0] * inv, o0[4 * g + 1] * inv);
            uv.y = cvtpk(o0[4 * g + 2] * inv, o0[4 * g + 3] * inv);
            *(uint2*)(ap + 8 * g + 4 * hi) = uv;
            uv.x = cvtpk(o1[4 * g + 0] * inv, o1[4 * g + 1] * inv);
            uv.y = cvtpk(o1[4 * g + 2] * inv, o1[4 * g + 3] * inv);
            *(uint2*)(ap + 32 + 8 * g + 4 * hi) = uv;
        }
    }
}

// ---------------------------------------------------------------------------
extern "C" void kernel_launch(void* const* d_in, const int* in_sizes, int n_in,
                              void* d_out, int out_size, void* d_ws, size_t ws_size,
                              hipStream_t stream)
{
    const float* q  = (const float*)d_in[0];
    const float* k  = (const float*)d_in[1];
    const float* v  = (const float*)d_in[2];
    const int*   pm = (const int*)d_in[3];
    const float* Wq = (const float*)d_in[4];
    const float* bq = (const float*)d_in[5];
    const float* Wk = (const float*)d_in[6];
    const float* bk = (const float*)d_in[7];
    const float* Wv = (const float*)d_in[8];
    const float* bv = (const float*)d_in[9];
    const float* Wo = (const float*)d_in[10];
    const float* bo = (const float*)d_in[11];
    float* out = (float*)d_out;

    const size_t WT_E = (size_t)1024 * 1024;      // per-weight bf16 elems (2 MiB)
    const size_t HB_E = (size_t)8192 * 1024;      // batched per-tensor elems (16 MiB)
    const size_t PB_E = (size_t)2048 * 1024;      // per-batch elems (4 MiB)

    ubf16* WtQ = (ubf16*)d_ws;
    ubf16* WtK = WtQ + WT_E;
    ubf16* WtV = WtK + WT_E;
    ubf16* WtO = WtV + WT_E;
    ubf16* base = WtO + WT_E;

    dim3 blk(256);
    dim3 gtr(16, 16);
    wtrans<<<gtr, blk, 0, stream>>>(Wq, WtQ);
    wtrans<<<gtr, blk, 0, stream>>>(Wk, WtK);
    wtrans<<<gtr, blk, 0, stream>>>(Wv, WtV);
    wtrans<<<gtr, blk, 0, stream>>>(Wo, WtO);

    const size_t need_batched = (4 * WT_E + 4 * HB_E) * sizeof(ubf16);  // 72 MiB
    if (ws_size >= need_batched) {
        ubf16* Qh = base;
        ubf16* Kh = Qh + HB_E;
        ubf16* Vt = Kh + HB_E;
        ubf16* Aw = Vt + HB_E;       // doubles as the bf16-convert staging buf
        dim3 gg(64, 8);              // M=8192, N=1024, 128x128 tiles
        const int n8 = (int)(HB_E / 8);
        cvt_bf16<<<n8 / 256, blk, 0, stream>>>(q, Aw, n8);
        gemm_mfma<0><<<gg, blk, 0, stream>>>(Aw, WtQ, bq, Qh);
        cvt_bf16<<<n8 / 256, blk, 0, stream>>>(k, Aw, n8);
        gemm_mfma<0><<<gg, blk, 0, stream>>>(Aw, WtK, bk, Kh);
        cvt_bf16<<<n8 / 256, blk, 0, stream>>>(v, Aw, n8);
        gemm_mfma<1><<<gg, blk, 0, stream>>>(Aw, WtV, bv, Vt);
        dim3 ga(8, HEADS, N_B);      // 512 blocks, paired q-tiles (34 tiles ea)
        attn_mfma<<<ga, blk, 0, stream>>>(Qh, Kh, Vt, pm, Aw);
        gemm_mfma<2><<<gg, blk, 0, stream>>>(Aw, WtO, bo, out);
    } else {
        // per-batch fallback (24 MiB workspace)
        ubf16* Qh = base;
        ubf16* Kh = Qh + PB_E;
        ubf16* Vt = Kh + PB_E;
        ubf16* Aw = Vt + PB_E;
        dim3 gg(16, 8);
        dim3 ga(8, HEADS, 1);
        const int n8 = (int)(PB_E / 8);
        for (int n = 0; n < N_B; ++n) {
            const size_t xoff = (size_t)n * T_S * DM;
            cvt_bf16<<<n8 / 256, blk, 0, stream>>>(q + xoff, Aw, n8);
            gemm_mfma<0><<<gg, blk, 0, stream>>>(Aw, WtQ, bq, Qh);
            cvt_bf16<<<n8 / 256, blk, 0, stream>>>(k + xoff, Aw, n8);
            gemm_mfma<0><<<gg, blk, 0, stream>>>(Aw, WtK, bk, Kh);
            cvt_bf16<<<n8 / 256, blk, 0, stream>>>(v + xoff, Aw, n8);
            gemm_mfma<1><<<gg, blk, 0, stream>>>(Aw, WtV, bv, Vt);
            attn_mfma<<<ga, blk, 0, stream>>>(Qh, Kh, Vt, pm + n * T_S, Aw);
            gemm_mfma<2><<<gg, blk, 0, stream>>>(Aw, WtO, bo, out + xoff);
        }
    }
}